// Round 1
// baseline (1111.121 us; speedup 1.0000x reference)
//
#include <hip/hip_runtime.h>
#include <math.h>

// DotProductAttention: B=64, S=1024, D=64, fp32 in/out, per-batch key mask.
// Round 0: correct fp32 flash-attention baseline (no score materialization).
// One block per (batch, 64-query tile); 256 threads; Q/K/V tiles in LDS.

#define BB 64
#define SS 1024
#define DD 64
#define QT 64      // queries per block
#define KT 64      // keys per inner tile
#define NKT (SS / KT)
#define PAD 68     // padded LDS row stride in floats (272 B: 16B-aligned, bank shift 4)

#define MASK_VALUE -1000000.0f

__global__ __launch_bounds__(256) void attn_fp32_flash(
    const float* __restrict__ q, const float* __restrict__ k,
    const float* __restrict__ v, const int* __restrict__ valid_lens,
    float* __restrict__ out)
{
    __shared__ float qs[QT][PAD];
    __shared__ float ks[KT][PAD];
    __shared__ float vs[KT][PAD];

    const int t = threadIdx.x;
    const int nqb = SS / QT;
    const int b = blockIdx.x / nqb;
    const int q0 = (blockIdx.x % nqb) * QT;
    const int vl = valid_lens[b];

    const size_t batch_off = (size_t)b * SS * DD;
    const float* qbase = q + batch_off + (size_t)q0 * DD;

    // Load Q tile: 4096 floats = 1024 float4; 256 threads x 4 each (coalesced).
    for (int i = 0; i < 4; i++) {
        int idx = t + i * 256;          // float4 index within tile
        int rr  = idx >> 4;             // 16 float4 per 64-float row
        int c4  = idx & 15;
        float4 val = ((const float4*)qbase)[idx];
        *((float4*)&qs[rr][c4 * 4]) = val;
    }

    // Thread -> (query row, key group). 4 consecutive lanes share a row.
    const int r  = t >> 2;     // 0..63
    const int cg = t & 3;      // 0..3  (keys cg*16 .. cg*16+15)

    float m = -INFINITY;
    float l = 0.0f;
    float4 acc[16];
    #pragma unroll
    for (int i = 0; i < 16; i++) acc[i] = make_float4(0.f, 0.f, 0.f, 0.f);

    for (int kt_ = 0; kt_ < NKT; kt_++) {
        __syncthreads();   // previous-iteration LDS reads done (also covers Q stores on iter 0)
        const float* kbase = k + batch_off + (size_t)kt_ * KT * DD;
        const float* vbase = v + batch_off + (size_t)kt_ * KT * DD;
        for (int i = 0; i < 4; i++) {
            int idx = t + i * 256;
            int rr  = idx >> 4;
            int c4  = idx & 15;
            ((float4*)&ks[rr][0])[c4] = ((const float4*)kbase)[idx];
            ((float4*)&vs[rr][0])[c4] = ((const float4*)vbase)[idx];
        }
        __syncthreads();

        // QK^T: 16 scores per thread.
        float s[16];
        const float4* qrow = (const float4*)&qs[r][0];
        #pragma unroll
        for (int j = 0; j < 16; j++) {
            int kc = cg * 16 + j;
            const float4* krow = (const float4*)&ks[kc][0];
            float a0 = 0.f, a1 = 0.f, a2 = 0.f, a3 = 0.f;
            #pragma unroll
            for (int d4 = 0; d4 < 16; d4++) {
                float4 a  = qrow[d4];
                float4 bb = krow[d4];
                a0 += a.x * bb.x; a1 += a.y * bb.y;
                a2 += a.z * bb.z; a3 += a.w * bb.w;
            }
            float dot = (a0 + a1) + (a2 + a3);
            int kglob = kt_ * KT + kc;
            s[j] = (kglob < vl) ? dot * 0.125f : MASK_VALUE;
        }

        // Online softmax across the row's 4 lanes (consecutive -> xor 1,2).
        float lm = s[0];
        #pragma unroll
        for (int j = 1; j < 16; j++) lm = fmaxf(lm, s[j]);
        lm = fmaxf(lm, __shfl_xor(lm, 1, 64));
        lm = fmaxf(lm, __shfl_xor(lm, 2, 64));
        float m_new = fmaxf(m, lm);
        float alpha = __expf(m - m_new);   // m=-inf on first tile -> alpha=0

        float p[16];
        float lsum = 0.f;
        #pragma unroll
        for (int j = 0; j < 16; j++) {
            p[j] = __expf(s[j] - m_new);
            lsum += p[j];
        }
        lsum += __shfl_xor(lsum, 1, 64);
        lsum += __shfl_xor(lsum, 2, 64);
        l = l * alpha + lsum;
        m = m_new;

        #pragma unroll
        for (int i = 0; i < 16; i++) {
            acc[i].x *= alpha; acc[i].y *= alpha;
            acc[i].z *= alpha; acc[i].w *= alpha;
        }

        // PV: acc[d] += p_j * v[key_j][d]
        #pragma unroll
        for (int j = 0; j < 16; j++) {
            int kc = cg * 16 + j;
            const float4* vrow = (const float4*)&vs[kc][0];
            float pj = p[j];
            #pragma unroll
            for (int d4 = 0; d4 < 16; d4++) {
                float4 vv = vrow[d4];
                acc[d4].x += pj * vv.x; acc[d4].y += pj * vv.y;
                acc[d4].z += pj * vv.z; acc[d4].w += pj * vv.w;
            }
        }
    }

    // Reduce partial O across the row's 4 lanes; then each lane owns 1/4 of dims.
    #pragma unroll
    for (int i = 0; i < 16; i++) {
        acc[i].x += __shfl_xor(acc[i].x, 1, 64);
        acc[i].y += __shfl_xor(acc[i].y, 1, 64);
        acc[i].z += __shfl_xor(acc[i].z, 1, 64);
        acc[i].w += __shfl_xor(acc[i].w, 1, 64);
        acc[i].x += __shfl_xor(acc[i].x, 2, 64);
        acc[i].y += __shfl_xor(acc[i].y, 2, 64);
        acc[i].z += __shfl_xor(acc[i].z, 2, 64);
        acc[i].w += __shfl_xor(acc[i].w, 2, 64);
    }

    const float inv = 1.0f / l;
    float* obase = out + batch_off + (size_t)(q0 + r) * DD;
    #pragma unroll
    for (int i = 0; i < 4; i++) {
        int d4 = cg * 4 + i;
        float4 o = acc[d4];
        o.x *= inv; o.y *= inv; o.z *= inv; o.w *= inv;
        ((float4*)obase)[d4] = o;
    }
}

extern "C" void kernel_launch(void* const* d_in, const int* in_sizes, int n_in,
                              void* d_out, int out_size, void* d_ws, size_t ws_size,
                              hipStream_t stream) {
    const float* q = (const float*)d_in[0];
    const float* k = (const float*)d_in[1];
    const float* v = (const float*)d_in[2];
    const int* valid_lens = (const int*)d_in[3];
    float* out = (float*)d_out;

    dim3 grid(BB * (SS / QT));
    dim3 block(256);
    attn_fp32_flash<<<grid, block, 0, stream>>>(q, k, v, valid_lens, out);
}

// Round 2
// 137.199 us; speedup vs baseline: 8.0986x; 8.0986x over previous
//
#include <hip/hip_runtime.h>
#include <math.h>

// DotProductAttention B=64,S=1024,D=64 fp32 -> bf16 MFMA flash attention.
// Block = 128 queries (4 waves x 32), iterate 64-key tiles with online softmax.
// S^T orientation (A=K, B=Q) so softmax rows = lane&15; P -> LDS (b64-packed)
// -> A-operand of PV; V staged transposed (d-major). All LDS strides 72 bf16
// (36 dwords === 4 mod 32: row aliasing <=2-way, rows 16B-aligned for b128).

#define BATCH 64
#define SEQ   1024
#define DIM   64
#define BQ    128          // queries per block
#define BC    64           // keys per iteration
#define NKT   (SEQ / BC)   // 16
#define LSTR  72           // LDS row stride in bf16 elements (144 B)

#define MASK_VALUE -1000000.0f

typedef __attribute__((ext_vector_type(8))) short bf16x8;
typedef __attribute__((ext_vector_type(4))) float f32x4;

__device__ __forceinline__ ushort f2bf(float x) {
    union { float f; uint u; } v; v.f = x;
    uint u = v.u;
    return (ushort)((u + 0x7fffu + ((u >> 16) & 1u)) >> 16);   // RNE
}

__global__ __launch_bounds__(256, 2) void attn_mfma_flash(
    const float* __restrict__ q, const float* __restrict__ k,
    const float* __restrict__ v, const int* __restrict__ valid_lens,
    float* __restrict__ out)
{
    __shared__ ushort Qs[BQ * LSTR];   // [query][d]
    __shared__ ushort Ks[BC * LSTR];   // [key][d]
    __shared__ ushort Vt[DIM * LSTR];  // [d][key]  (transposed V)
    __shared__ ushort Ps[BQ * LSTR];   // [query][key]  per-wave private rows

    const int t    = threadIdx.x;
    const int wave = t >> 6;
    const int wl   = t & 63;
    const int QD   = wl >> 4;          // quad 0..3
    const int li   = wl & 15;          // lane-in-quad 0..15
    const int b    = blockIdx.x >> 3;
    const int q0   = (blockIdx.x & 7) * BQ;
    const int vl   = valid_lens[b];
    const int qw   = wave * 32;        // wave's query base within block

    const size_t boff = (size_t)b * SEQ * DIM;

    // ---- stage Q once (block-wide, coalesced float4, cvt to bf16) ----
    {
        const float4* qg = (const float4*)(q + boff + (size_t)q0 * DIM);
        #pragma unroll
        for (int i = 0; i < 8; i++) {
            int idx = t + 256 * i;       // 2048 float4 total
            int row = idx >> 4;
            int c4  = idx & 15;
            float4 val = qg[idx];
            ushort4 pk;
            pk.x = f2bf(val.x); pk.y = f2bf(val.y);
            pk.z = f2bf(val.z); pk.w = f2bf(val.w);
            *(ushort4*)&Qs[row * LSTR + c4 * 4] = pk;
        }
    }

    const int it_max = (vl == 0) ? NKT : ((vl + BC - 1) >> 6);

    float m_run[2] = {-INFINITY, -INFINITY};   // per-lane: queries qw+nt*16+li
    float l_run[2] = {0.f, 0.f};
    f32x4 acc_o[2][4];                          // [qtile][dtile], C-layout rows=QD*4+reg
    #pragma unroll
    for (int a = 0; a < 2; a++)
        #pragma unroll
        for (int d = 0; d < 4; d++)
            acc_o[a][d] = (f32x4){0.f, 0.f, 0.f, 0.f};

    for (int it = 0; it < it_max; it++) {
        __syncthreads();   // previous iteration's K/V reads complete

        // ---- stage K row-major ----
        {
            const float4* kg = (const float4*)(k + boff + (size_t)it * BC * DIM);
            #pragma unroll
            for (int i = 0; i < 4; i++) {
                int idx = t + 256 * i;   // 1024 float4
                int row = idx >> 4;
                int c4  = idx & 15;
                float4 val = kg[idx];
                ushort4 pk;
                pk.x = f2bf(val.x); pk.y = f2bf(val.y);
                pk.z = f2bf(val.z); pk.w = f2bf(val.w);
                *(ushort4*)&Ks[row * LSTR + c4 * 4] = pk;
            }
            // ---- stage V transposed: key-pairs -> packed b32 writes ----
            const float4* vg = (const float4*)(v + boff + (size_t)it * BC * DIM);
            #pragma unroll
            for (int i = 0; i < 2; i++) {
                int slot = t + 256 * i;  // 512 slots = 32 keypairs x 16 d-groups
                int kp = slot >> 4;
                int c4 = slot & 15;
                float4 v0 = vg[(2 * kp) * 16 + c4];
                float4 v1 = vg[(2 * kp + 1) * 16 + c4];
                ushort2 w0 = {f2bf(v0.x), f2bf(v1.x)};
                ushort2 w1 = {f2bf(v0.y), f2bf(v1.y)};
                ushort2 w2 = {f2bf(v0.z), f2bf(v1.z)};
                ushort2 w3 = {f2bf(v0.w), f2bf(v1.w)};
                *(ushort2*)&Vt[(c4 * 4 + 0) * LSTR + 2 * kp] = w0;
                *(ushort2*)&Vt[(c4 * 4 + 1) * LSTR + 2 * kp] = w1;
                *(ushort2*)&Vt[(c4 * 4 + 2) * LSTR + 2 * kp] = w2;
                *(ushort2*)&Vt[(c4 * 4 + 3) * LSTR + 2 * kp] = w3;
            }
        }
        __syncthreads();

        // ---- QK^T as S^T: D[key][query] = K x Q^T ----
        f32x4 sc[4][2];
        {
            bf16x8 qb[2][2], ka[4][2];
            #pragma unroll
            for (int nt = 0; nt < 2; nt++)
                #pragma unroll
                for (int kc = 0; kc < 2; kc++)
                    qb[nt][kc] = *(const bf16x8*)&Qs[(qw + nt * 16 + li) * LSTR + kc * 32 + QD * 8];
            #pragma unroll
            for (int kt = 0; kt < 4; kt++)
                #pragma unroll
                for (int kc = 0; kc < 2; kc++)
                    ka[kt][kc] = *(const bf16x8*)&Ks[(kt * 16 + li) * LSTR + kc * 32 + QD * 8];
            #pragma unroll
            for (int kt = 0; kt < 4; kt++)
                #pragma unroll
                for (int nt = 0; nt < 2; nt++) {
                    f32x4 c = (f32x4){0.f, 0.f, 0.f, 0.f};
                    c = __builtin_amdgcn_mfma_f32_16x16x32_bf16(ka[kt][0], qb[nt][0], c, 0, 0, 0);
                    c = __builtin_amdgcn_mfma_f32_16x16x32_bf16(ka[kt][1], qb[nt][1], c, 0, 0, 0);
                    sc[kt][nt] = c;
                }
        }

        // ---- scale + mask + online softmax (row = query = li) ----
        const int kbase = it * BC;
        float mt_[2] = {-INFINITY, -INFINITY};
        #pragma unroll
        for (int kt = 0; kt < 4; kt++)
            #pragma unroll
            for (int nt = 0; nt < 2; nt++)
                #pragma unroll
                for (int r = 0; r < 4; r++) {
                    int key = kbase + kt * 16 + QD * 4 + r;
                    float x = (key < vl) ? sc[kt][nt][r] * 0.125f : MASK_VALUE;
                    sc[kt][nt][r] = x;
                    mt_[nt] = fmaxf(mt_[nt], x);
                }
        #pragma unroll
        for (int nt = 0; nt < 2; nt++) {
            mt_[nt] = fmaxf(mt_[nt], __shfl_xor(mt_[nt], 16, 64));
            mt_[nt] = fmaxf(mt_[nt], __shfl_xor(mt_[nt], 32, 64));
        }

        float alpha[2], ls[2];
        #pragma unroll
        for (int nt = 0; nt < 2; nt++) {
            float mn = fmaxf(m_run[nt], mt_[nt]);     // finite: every tile has >= MASK_VALUE
            alpha[nt] = __expf(m_run[nt] - mn);       // -inf - finite -> 0 on first tile
            m_run[nt] = mn;
            ls[nt] = 0.f;
        }

        // p = exp(s - m), pack 4 consecutive keys -> one b64 store into Ps
        #pragma unroll
        for (int kt = 0; kt < 4; kt++)
            #pragma unroll
            for (int nt = 0; nt < 2; nt++) {
                float p0 = __expf(sc[kt][nt][0] - m_run[nt]);
                float p1 = __expf(sc[kt][nt][1] - m_run[nt]);
                float p2 = __expf(sc[kt][nt][2] - m_run[nt]);
                float p3 = __expf(sc[kt][nt][3] - m_run[nt]);
                ls[nt] += (p0 + p1) + (p2 + p3);
                ushort4 pk = {f2bf(p0), f2bf(p1), f2bf(p2), f2bf(p3)};
                *(ushort4*)&Ps[(qw + nt * 16 + li) * LSTR + kt * 16 + QD * 4] = pk;
            }

        #pragma unroll
        for (int nt = 0; nt < 2; nt++) {
            ls[nt] += __shfl_xor(ls[nt], 16, 64);
            ls[nt] += __shfl_xor(ls[nt], 32, 64);
            l_run[nt] = l_run[nt] * alpha[nt] + ls[nt];
        }

        // rescale O accumulator: O rows are QD*4+r -> fetch alpha via shuffle
        #pragma unroll
        for (int qt = 0; qt < 2; qt++) {
            float a0 = __shfl(alpha[qt], QD * 4 + 0, 64);
            float a1 = __shfl(alpha[qt], QD * 4 + 1, 64);
            float a2 = __shfl(alpha[qt], QD * 4 + 2, 64);
            float a3 = __shfl(alpha[qt], QD * 4 + 3, 64);
            #pragma unroll
            for (int dt = 0; dt < 4; dt++) {
                acc_o[qt][dt][0] *= a0;
                acc_o[qt][dt][1] *= a1;
                acc_o[qt][dt][2] *= a2;
                acc_o[qt][dt][3] *= a3;
            }
        }

        // ---- PV: O[query][d] += P x V  (P from Ps, V from Vt; same-wave LDS, no barrier) ----
        {
            bf16x8 pa[2][2], vb[4][2];
            #pragma unroll
            for (int qt = 0; qt < 2; qt++)
                #pragma unroll
                for (int kc = 0; kc < 2; kc++)
                    pa[qt][kc] = *(const bf16x8*)&Ps[(qw + qt * 16 + li) * LSTR + kc * 32 + QD * 8];
            #pragma unroll
            for (int dt = 0; dt < 4; dt++)
                #pragma unroll
                for (int kc = 0; kc < 2; kc++)
                    vb[dt][kc] = *(const bf16x8*)&Vt[(dt * 16 + li) * LSTR + kc * 32 + QD * 8];
            #pragma unroll
            for (int qt = 0; qt < 2; qt++)
                #pragma unroll
                for (int dt = 0; dt < 4; dt++) {
                    acc_o[qt][dt] = __builtin_amdgcn_mfma_f32_16x16x32_bf16(pa[qt][0], vb[dt][0], acc_o[qt][dt], 0, 0, 0);
                    acc_o[qt][dt] = __builtin_amdgcn_mfma_f32_16x16x32_bf16(pa[qt][1], vb[dt][1], acc_o[qt][dt], 0, 0, 0);
                }
        }
    }

    // ---- epilogue: O /= l, store fp32 ----
    float invl[2];
    #pragma unroll
    for (int qt = 0; qt < 2; qt++) invl[qt] = 1.0f / l_run[qt];

    float* ob = out + boff + (size_t)q0 * DIM;
    #pragma unroll
    for (int qt = 0; qt < 2; qt++) {
        float i0 = __shfl(invl[qt], QD * 4 + 0, 64);
        float i1 = __shfl(invl[qt], QD * 4 + 1, 64);
        float i2 = __shfl(invl[qt], QD * 4 + 2, 64);
        float i3 = __shfl(invl[qt], QD * 4 + 3, 64);
        #pragma unroll
        for (int dt = 0; dt < 4; dt++) {
            int col = dt * 16 + li;
            ob[(size_t)(qw + qt * 16 + QD * 4 + 0) * DIM + col] = acc_o[qt][dt][0] * i0;
            ob[(size_t)(qw + qt * 16 + QD * 4 + 1) * DIM + col] = acc_o[qt][dt][1] * i1;
            ob[(size_t)(qw + qt * 16 + QD * 4 + 2) * DIM + col] = acc_o[qt][dt][2] * i2;
            ob[(size_t)(qw + qt * 16 + QD * 4 + 3) * DIM + col] = acc_o[qt][dt][3] * i3;
        }
    }
}

extern "C" void kernel_launch(void* const* d_in, const int* in_sizes, int n_in,
                              void* d_out, int out_size, void* d_ws, size_t ws_size,
                              hipStream_t stream) {
    const float* q = (const float*)d_in[0];
    const float* k = (const float*)d_in[1];
    const float* v = (const float*)d_in[2];
    const int* valid_lens = (const int*)d_in[3];
    float* out = (float*)d_out;

    dim3 grid(BATCH * (SEQ / BQ));   // 64 x 8 = 512 blocks
    dim3 block(256);
    attn_mfma_flash<<<grid, block, 0, stream>>>(q, k, v, valid_lens, out);
}

// Round 3
// 127.545 us; speedup vs baseline: 8.7116x; 1.0757x over previous
//
#include <hip/hip_runtime.h>
#include <math.h>

// DotProductAttention B=64,S=1024,D=64 fp32, bf16-MFMA flash attention.
// Round 2: latency attack. BQ=64 -> 1024 blocks (4/CU); Q fragments in
// registers (no Q LDS); K/V register-prefetch pipeline; exp2-domain softmax
// (0.125*log2e folded into Q); perm-truncation bf16 packs; V staged with
// b128 row writes (bank-uniform); batch-major block swizzle -> K/V L2-resident
// per XCD. LDS = 3 x 64 x 72 ushort = 27.6 KB.

#define BATCH 64
#define SEQ   1024
#define DIM   64
#define BQ    64           // queries per block (4 waves x 16)
#define BC    64           // keys per iteration
#define NKT   (SEQ / BC)   // 16
#define LSTR  72           // LDS row stride in bf16 (144 B = 36 dwords === 4 mod 32)
#define QSCALE 0.18033688011112442f   // 0.125 * log2(e)
#define MASKED -1.0e6f

typedef __attribute__((ext_vector_type(8))) short bf16x8;
typedef __attribute__((ext_vector_type(4))) float f32x4;

__device__ __forceinline__ uint pack2_trunc(float lo, float hi) {
    // [bf16(hi) : bf16(lo)] by byte-select (truncation) — one v_perm_b32
    return __builtin_amdgcn_perm(__float_as_uint(hi), __float_as_uint(lo), 0x07060302);
}
__device__ __forceinline__ ushort f2bf_rne(float x) {
    uint u = __float_as_uint(x);
    return (ushort)((u + 0x7fffu + ((u >> 16) & 1u)) >> 16);
}

__global__ __launch_bounds__(256, 4) void attn_mfma_flash2(
    const float* __restrict__ q, const float* __restrict__ k,
    const float* __restrict__ v, const int* __restrict__ valid_lens,
    float* __restrict__ out)
{
    __shared__ ushort Ks[BC * LSTR];   // [key][d]
    __shared__ ushort Vt[DIM * LSTR];  // [d][key]
    __shared__ ushort Ps[BQ * LSTR];   // [query][key], wave-private 16-row bands

    const int t    = threadIdx.x;
    const int wave = t >> 6;
    const int wl   = t & 63;
    const int QD   = wl >> 4;          // quad 0..3
    const int li   = wl & 15;          // lane-in-quad 0..15
    // batch-major swizzle: all 16 q-tiles of a batch land on the same XCD
    const int b    = blockIdx.x & 63;
    const int q0   = (blockIdx.x >> 6) * BQ;
    const int vl   = valid_lens[b];

    const size_t boff = (size_t)b * SEQ * DIM;

    // ---- Q fragments straight into registers (B-operand), pre-scaled ----
    bf16x8 qb[2];
    {
        const float* qrow = q + boff + (size_t)(q0 + wave * 16 + li) * DIM + QD * 8;
        #pragma unroll
        for (int kc = 0; kc < 2; kc++) {
            float4 a = *(const float4*)(qrow + kc * 32);
            float4 c = *(const float4*)(qrow + kc * 32 + 4);
            union { bf16x8 v; ushort u[8]; } tmp;
            tmp.u[0] = f2bf_rne(a.x * QSCALE);
            tmp.u[1] = f2bf_rne(a.y * QSCALE);
            tmp.u[2] = f2bf_rne(a.z * QSCALE);
            tmp.u[3] = f2bf_rne(a.w * QSCALE);
            tmp.u[4] = f2bf_rne(c.x * QSCALE);
            tmp.u[5] = f2bf_rne(c.y * QSCALE);
            tmp.u[6] = f2bf_rne(c.z * QSCALE);
            tmp.u[7] = f2bf_rne(c.w * QSCALE);
            qb[kc] = tmp.v;
        }
    }

    const int it_max = (vl == 0) ? NKT : ((vl + BC - 1) >> 6);

    // ---- prefetch registers ----
    float4 kf[4];          // K tile: 4 coalesced float4 per thread
    float  vf[2][8];       // V gather: (d = lane, 8 consecutive keys) x 2 slots

    auto load_tile = [&](int it) {
        const float4* kg = (const float4*)(k + boff + (size_t)it * BC * DIM);
        #pragma unroll
        for (int i = 0; i < 4; i++) kf[i] = kg[t + 256 * i];
        const float* vgf = v + boff + (size_t)it * BC * DIM;
        #pragma unroll
        for (int i = 0; i < 2; i++) {
            int slot = t + 256 * i;
            int d = slot & 63, ko = slot >> 6;
            #pragma unroll
            for (int j = 0; j < 8; j++)
                vf[i][j] = vgf[(size_t)(ko * 8 + j) * DIM + d];
        }
    };

    auto stage = [&]() {
        #pragma unroll
        for (int i = 0; i < 4; i++) {
            int idx = t + 256 * i;
            int row = idx >> 4, c4 = idx & 15;
            uint2 w;
            w.x = pack2_trunc(kf[i].x, kf[i].y);
            w.y = pack2_trunc(kf[i].z, kf[i].w);
            *(uint2*)&Ks[row * LSTR + c4 * 4] = w;
        }
        #pragma unroll
        for (int i = 0; i < 2; i++) {
            int slot = t + 256 * i;
            int d = slot & 63, ko = slot >> 6;
            uint4 w;
            w.x = pack2_trunc(vf[i][0], vf[i][1]);
            w.y = pack2_trunc(vf[i][2], vf[i][3]);
            w.z = pack2_trunc(vf[i][4], vf[i][5]);
            w.w = pack2_trunc(vf[i][6], vf[i][7]);
            *(uint4*)&Vt[d * LSTR + ko * 8] = w;   // b128, bank-uniform
        }
    };

    float m_run = -INFINITY, l_run = 0.f;
    f32x4 acc[4];
    #pragma unroll
    for (int dt = 0; dt < 4; dt++) acc[dt] = (f32x4){0.f, 0.f, 0.f, 0.f};

    load_tile(0);

    for (int it = 0; it < it_max; it++) {
        __syncthreads();                  // prior tile's LDS reads done
        stage();
        if (it + 1 < it_max) load_tile(it + 1);   // in flight across compute
        __syncthreads();

        // ---- S^T = K x Q^T : rows = keys (QD*4+r), cols = queries (li) ----
        f32x4 sc[4];
        #pragma unroll
        for (int kt = 0; kt < 4; kt++) {
            bf16x8 ka0 = *(const bf16x8*)&Ks[(kt * 16 + li) * LSTR + QD * 8];
            bf16x8 ka1 = *(const bf16x8*)&Ks[(kt * 16 + li) * LSTR + 32 + QD * 8];
            f32x4 c = (f32x4){0.f, 0.f, 0.f, 0.f};
            c = __builtin_amdgcn_mfma_f32_16x16x32_bf16(ka0, qb[0], c, 0, 0, 0);
            c = __builtin_amdgcn_mfma_f32_16x16x32_bf16(ka1, qb[1], c, 0, 0, 0);
            sc[kt] = c;
        }

        // ---- mask (only the boundary/invalid tiles pay per-element cost) ----
        const int kbase = it * BC;
        if (kbase + BC > vl) {
            #pragma unroll
            for (int kt = 0; kt < 4; kt++)
                #pragma unroll
                for (int r = 0; r < 4; r++) {
                    int key = kbase + kt * 16 + QD * 4 + r;
                    if (key >= vl) sc[kt][r] = MASKED;
                }
        }

        // ---- online softmax in exp2 domain (row = query = li) ----
        float mt = -INFINITY;
        #pragma unroll
        for (int kt = 0; kt < 4; kt++)
            #pragma unroll
            for (int r = 0; r < 4; r++) mt = fmaxf(mt, sc[kt][r]);
        mt = fmaxf(mt, __shfl_xor(mt, 16, 64));
        mt = fmaxf(mt, __shfl_xor(mt, 32, 64));
        float mn = fmaxf(m_run, mt);
        float alpha = exp2f(m_run - mn);   // -inf on first tile -> 0
        m_run = mn;

        float ls = 0.f;
        #pragma unroll
        for (int kt = 0; kt < 4; kt++) {
            float p0 = exp2f(sc[kt][0] - mn);
            float p1 = exp2f(sc[kt][1] - mn);
            float p2 = exp2f(sc[kt][2] - mn);
            float p3 = exp2f(sc[kt][3] - mn);
            ls += (p0 + p1) + (p2 + p3);
            uint2 w;
            w.x = pack2_trunc(p0, p1);
            w.y = pack2_trunc(p2, p3);
            *(uint2*)&Ps[(wave * 16 + li) * LSTR + kt * 16 + QD * 4] = w;
        }
        ls += __shfl_xor(ls, 16, 64);
        ls += __shfl_xor(ls, 32, 64);
        l_run = l_run * alpha + ls;

        // rescale O accumulator rows (row = QD*4+r holds query QD*4+r)
        float a0 = __shfl(alpha, QD * 4 + 0, 64);
        float a1 = __shfl(alpha, QD * 4 + 1, 64);
        float a2 = __shfl(alpha, QD * 4 + 2, 64);
        float a3 = __shfl(alpha, QD * 4 + 3, 64);
        #pragma unroll
        for (int dt = 0; dt < 4; dt++) {
            acc[dt][0] *= a0; acc[dt][1] *= a1;
            acc[dt][2] *= a2; acc[dt][3] *= a3;
        }

        // ---- PV: O += P x V (same-wave LDS round-trip for P) ----
        bf16x8 pa0 = *(const bf16x8*)&Ps[(wave * 16 + li) * LSTR + QD * 8];
        bf16x8 pa1 = *(const bf16x8*)&Ps[(wave * 16 + li) * LSTR + 32 + QD * 8];
        #pragma unroll
        for (int dt = 0; dt < 4; dt++) {
            bf16x8 vb0 = *(const bf16x8*)&Vt[(dt * 16 + li) * LSTR + QD * 8];
            bf16x8 vb1 = *(const bf16x8*)&Vt[(dt * 16 + li) * LSTR + 32 + QD * 8];
            acc[dt] = __builtin_amdgcn_mfma_f32_16x16x32_bf16(pa0, vb0, acc[dt], 0, 0, 0);
            acc[dt] = __builtin_amdgcn_mfma_f32_16x16x32_bf16(pa1, vb1, acc[dt], 0, 0, 0);
        }
    }

    // ---- epilogue ----
    float invl = 1.0f / l_run;
    float i0 = __shfl(invl, QD * 4 + 0, 64);
    float i1 = __shfl(invl, QD * 4 + 1, 64);
    float i2 = __shfl(invl, QD * 4 + 2, 64);
    float i3 = __shfl(invl, QD * 4 + 3, 64);
    float* ob = out + boff + (size_t)q0 * DIM;
    const int rbase = wave * 16 + QD * 4;
    #pragma unroll
    for (int dt = 0; dt < 4; dt++) {
        int col = dt * 16 + li;
        ob[(size_t)(rbase + 0) * DIM + col] = acc[dt][0] * i0;
        ob[(size_t)(rbase + 1) * DIM + col] = acc[dt][1] * i1;
        ob[(size_t)(rbase + 2) * DIM + col] = acc[dt][2] * i2;
        ob[(size_t)(rbase + 3) * DIM + col] = acc[dt][3] * i3;
    }
}

extern "C" void kernel_launch(void* const* d_in, const int* in_sizes, int n_in,
                              void* d_out, int out_size, void* d_ws, size_t ws_size,
                              hipStream_t stream) {
    const float* q = (const float*)d_in[0];
    const float* k = (const float*)d_in[1];
    const float* v = (const float*)d_in[2];
    const int* valid_lens = (const int*)d_in[3];
    float* out = (float*)d_out;

    dim3 grid(BATCH * (SEQ / BQ));   // 64 x 16 = 1024 blocks
    dim3 block(256);
    attn_mfma_flash2<<<grid, block, 0, stream>>>(q, k, v, valid_lens, out);
}